// Round 3
// baseline (384.662 us; speedup 1.0000x reference)
//
#include <hip/hip_runtime.h>
#include <hip/hip_bf16.h>

// B=2, S=2048, D=1024, H=16, dk=64. Inputs/outputs fp32; compute in bf16 MFMA.
// ws layout (bf16): q 0..8M, k 8M..16M, vt 16M..24M, ctx 24M..32M (bytes)
#define SEQ 2048
#define DIM 1024
#define NH  16
#define DK  64

typedef __attribute__((ext_vector_type(4))) float f32x4;
typedef __attribute__((ext_vector_type(8))) __bf16 bf16x8;

__device__ __forceinline__ f32x4 mfma16(bf16x8 a, bf16x8 b, f32x4 c) {
  return __builtin_amdgcn_mfma_f32_16x16x32_bf16(a, b, c, 0, 0, 0);
}

// load 8 fp32 from global, convert to bf16, store 16B to LDS
__device__ __forceinline__ void cvt_store8(const float* __restrict__ g, void* l) {
  float4 a = ((const float4*)g)[0];
  float4 b = ((const float4*)g)[1];
  bf16x8 v = {(__bf16)a.x, (__bf16)a.y, (__bf16)a.z, (__bf16)a.w,
              (__bf16)b.x, (__bf16)b.y, (__bf16)b.z, (__bf16)b.w};
  *(bf16x8*)l = v;
}

// plain 16B copy (bf16 source already)
__device__ __forceinline__ void copy16(const void* g, void* l) {
  *(uint4*)l = *(const uint4*)g;
}

// ---------------------------------------------------------------------------
// 128x128 C-tile GEMM mainloop: C = X(M,1024) @ W(1024,1024)^T  (NT GEMM).
// X may be fp32 (converted during staging) or bf16; W likewise.
// 256 threads = 4 waves, each wave a 64x64 sub-tile (4x4 MFMA 16x16x32).
// ---------------------------------------------------------------------------
template <bool X_F32, bool W_F32>
__device__ __forceinline__ void gemm_mainloop(
    const void* __restrict__ Xv, const void* __restrict__ Wv,
    __hip_bfloat16* A_lds, __hip_bfloat16* B_lds, int m0, int n0,
    f32x4 acc[4][4]) {
  const int K = DIM;
  const int tid = threadIdx.x;
  const int lane = tid & 63;
  const int w = tid >> 6;
  const int quad = lane >> 4, l15 = lane & 15;
  const int wm = (w >> 1) * 64, wn = (w & 1) * 64;

  f32x4 z = {0.f, 0.f, 0.f, 0.f};
  for (int mi = 0; mi < 4; ++mi)
    for (int ni = 0; ni < 4; ++ni) acc[mi][ni] = z;

  for (int k0 = 0; k0 < K; k0 += 64) {
    // stage A-tile (128x64) and B-tile: 1024 x (8 bf16) chunks each.
    for (int r = 0; r < 4; ++r) {
      int c = r * 256 + tid;          // chunk id
      int row = c >> 3, off = c & 7;  // 8 chunks per 64-elem row
      if (X_F32)
        cvt_store8((const float*)Xv + (size_t)(m0 + row) * K + k0 + off * 8,
                   (char*)A_lds + c * 16);
      else
        copy16((const char*)((const __hip_bfloat16*)Xv + (size_t)(m0 + row) * K + k0) + off * 16,
               (char*)A_lds + c * 16);
      if (W_F32)
        cvt_store8((const float*)Wv + (size_t)(n0 + row) * K + k0 + off * 8,
                   (char*)B_lds + c * 16);
      else
        copy16((const char*)((const __hip_bfloat16*)Wv + (size_t)(n0 + row) * K + k0) + off * 16,
               (char*)B_lds + c * 16);
    }
    __syncthreads();  // staging visible
    for (int kk = 0; kk < 2; ++kk) {
      bf16x8 a[4], b[4];
      for (int mi = 0; mi < 4; ++mi)
        a[mi] = *(const bf16x8*)(A_lds + (wm + mi * 16 + l15) * 64 + kk * 32 + quad * 8);
      for (int ni = 0; ni < 4; ++ni)
        b[ni] = *(const bf16x8*)(B_lds + (wn + ni * 16 + l15) * 64 + kk * 32 + quad * 8);
      for (int mi = 0; mi < 4; ++mi)
        for (int ni = 0; ni < 4; ++ni)
          acc[mi][ni] = mfma16(a[mi], b[ni], acc[mi][ni]);
    }
    __syncthreads();  // reads done before restage
  }
}

// ---------------------------------------------------------------------------
// Fused QKV projection. grid = (8, 32, 3); z selects q/k/v.
// q,k written (B,H,S,dk) bf16; v written transposed (B,H,dk,S) bf16.
// ---------------------------------------------------------------------------
__global__ __launch_bounds__(256) void qkv_proj_kernel(
    const float* __restrict__ q_in, const float* __restrict__ k_in,
    const float* __restrict__ v_in,
    const float* __restrict__ wq, const float* __restrict__ wk,
    const float* __restrict__ wv,
    const float* __restrict__ bq, const float* __restrict__ bk,
    const float* __restrict__ bv,
    __hip_bfloat16* __restrict__ q_ws, __hip_bfloat16* __restrict__ k_ws,
    __hip_bfloat16* __restrict__ vt_ws) {
  __shared__ __align__(16) __hip_bfloat16 A_lds[128 * 64];
  __shared__ __align__(16) __hip_bfloat16 B_lds[128 * 64];

  const int z = blockIdx.z;
  const float* X = (z == 0) ? q_in : ((z == 1) ? k_in : v_in);
  const float* W = (z == 0) ? wq : ((z == 1) ? wk : wv);
  const float* bias = (z == 0) ? bq : ((z == 1) ? bk : bv);
  __hip_bfloat16* out = (z == 0) ? q_ws : ((z == 1) ? k_ws : vt_ws);

  const int m0 = blockIdx.y * 128, n0 = blockIdx.x * 128;
  f32x4 acc[4][4];
  gemm_mainloop<true, true>(X, W, A_lds, B_lds, m0, n0, acc);

  const int tid = threadIdx.x, lane = tid & 63, w = tid >> 6;
  const int quad = lane >> 4, l15 = lane & 15;
  const int wm = (w >> 1) * 64, wn = (w & 1) * 64;

  for (int mi = 0; mi < 4; ++mi)
    for (int ni = 0; ni < 4; ++ni) {
      const int n = n0 + wn + ni * 16 + l15;
      const float bv_ = bias[n];
      const int h = n >> 6, d = n & 63;
      for (int r = 0; r < 4; ++r) {
        const int m = m0 + wm + mi * 16 + quad * 4 + r;
        const int b = m >> 11, s = m & 2047;
        const float v = acc[mi][ni][r] + bv_;
        size_t addr;
        if (z == 2)
          addr = ((size_t)(b * NH + h) * DK + d) * SEQ + s;   // v transposed
        else
          addr = ((size_t)(b * NH + h) * SEQ + s) * DK + d;   // q,k
        out[addr] = __float2bfloat16(v);
      }
    }
}

// ---------------------------------------------------------------------------
// Flash attention. grid = (S/128=16, B*H=32). 256 threads = 4 waves,
// wave w owns q-rows [w*32, w*32+32). Online softmax in registers.
// All tensors here are bf16 ws; ctx written bf16.
// ---------------------------------------------------------------------------
__global__ __launch_bounds__(256) void attn_kernel(
    const __hip_bfloat16* __restrict__ qg, const __hip_bfloat16* __restrict__ kg,
    const __hip_bfloat16* __restrict__ vtg, const int* __restrict__ mask,
    __hip_bfloat16* __restrict__ ctx) {
  __shared__ __align__(16) __hip_bfloat16 Q_lds[128 * 64];
  __shared__ __align__(16) __hip_bfloat16 K_lds[64 * 64];
  __shared__ __align__(16) __hip_bfloat16 V_lds[64 * 64];  // V^T tile: [d][s]
  __shared__ __align__(16) __hip_bfloat16 P_lds[128 * 64];
  __shared__ int mask_lds[SEQ];

  const int tid = threadIdx.x, lane = tid & 63, w = tid >> 6;
  const int quad = lane >> 4, l15 = lane & 15;
  const int bh = blockIdx.y, b = bh >> 4, h = bh & 15;
  const int q0 = blockIdx.x * 128;
  const size_t head = (size_t)bh * SEQ * DK;

  for (int i = tid; i < SEQ; i += 256) mask_lds[i] = mask[b * SEQ + i];

  // stage Q tile (128x64): 1024 chunks
  for (int r = 0; r < 4; ++r) {
    int c = r * 256 + tid;
    int row = c >> 3, off = c & 7;
    copy16((const char*)(qg + head + (size_t)(q0 + row) * DK) + off * 16,
           (char*)Q_lds + c * 16);
  }
  __syncthreads();

  int qm[2][4];
  for (int mi = 0; mi < 2; ++mi)
    for (int r = 0; r < 4; ++r)
      qm[mi][r] = mask_lds[q0 + w * 32 + mi * 16 + quad * 4 + r];

  f32x4 z = {0.f, 0.f, 0.f, 0.f};
  f32x4 o_acc[2][4];
  for (int mi = 0; mi < 2; ++mi)
    for (int di = 0; di < 4; ++di) o_acc[mi][di] = z;
  float m_run[2][4], l_run[2][4], alpha[2][4];
  for (int mi = 0; mi < 2; ++mi)
    for (int r = 0; r < 4; ++r) { m_run[mi][r] = -1e30f; l_run[mi][r] = 0.f; }

  for (int t = 0; t < 32; ++t) {
    const int k0 = t * 64;
    // stage K tile (64 keys x 64 dk) and V^T tile (64 dk x 64 keys)
    for (int r = 0; r < 2; ++r) {
      int c = r * 256 + tid;
      int row = c >> 3, off = c & 7;
      copy16((const char*)(kg + head + (size_t)(k0 + row) * DK) + off * 16,
             (char*)K_lds + c * 16);
      copy16((const char*)(vtg + (size_t)bh * DK * SEQ + (size_t)row * SEQ + k0) + off * 16,
             (char*)V_lds + c * 16);
    }
    __syncthreads();  // staging visible

    // S = Q K^T  (wave: 32 rows x 64 keys)
    f32x4 s_acc[2][4];
    for (int mi = 0; mi < 2; ++mi)
      for (int ni = 0; ni < 4; ++ni) s_acc[mi][ni] = z;
    for (int kk = 0; kk < 2; ++kk) {
      bf16x8 a[2], bb[4];
      for (int mi = 0; mi < 2; ++mi)
        a[mi] = *(const bf16x8*)(Q_lds + (w * 32 + mi * 16 + l15) * 64 + kk * 32 + quad * 8);
      for (int ni = 0; ni < 4; ++ni)
        bb[ni] = *(const bf16x8*)(K_lds + (ni * 16 + l15) * 64 + kk * 32 + quad * 8);
      for (int mi = 0; mi < 2; ++mi)
        for (int ni = 0; ni < 4; ++ni)
          s_acc[mi][ni] = mfma16(a[mi], bb[ni], s_acc[mi][ni]);
    }

    // mask + scale. C-layout: row = quad*4+r (+mi*16), col = ni*16+l15
    int km[4];
    for (int ni = 0; ni < 4; ++ni) km[ni] = mask_lds[k0 + ni * 16 + l15];
    for (int mi = 0; mi < 2; ++mi)
      for (int ni = 0; ni < 4; ++ni)
        for (int r = 0; r < 4; ++r) {
          float sv = s_acc[mi][ni][r];
          s_acc[mi][ni][r] = (km[ni] != 0 && qm[mi][r] != 0) ? sv * 0.125f : -1e9f;
        }

    // online softmax per row; the 16 lanes of a quad share a row
    for (int mi = 0; mi < 2; ++mi)
      for (int r = 0; r < 4; ++r) {
        float mx = fmaxf(fmaxf(s_acc[mi][0][r], s_acc[mi][1][r]),
                         fmaxf(s_acc[mi][2][r], s_acc[mi][3][r]));
        for (int o = 1; o < 16; o <<= 1) mx = fmaxf(mx, __shfl_xor(mx, o));
        float mnew = fmaxf(m_run[mi][r], mx);
        float al = __expf(m_run[mi][r] - mnew);
        float sum = 0.f;
        for (int ni = 0; ni < 4; ++ni) {
          float p = __expf(s_acc[mi][ni][r] - mnew);
          s_acc[mi][ni][r] = p;
          sum += p;
        }
        for (int o = 1; o < 16; o <<= 1) sum += __shfl_xor(sum, o);
        l_run[mi][r] = al * l_run[mi][r] + sum;
        m_run[mi][r] = mnew;
        alpha[mi][r] = al;
      }

    // write P (C-layout -> LDS row-major), rescale O
    for (int mi = 0; mi < 2; ++mi)
      for (int ni = 0; ni < 4; ++ni)
        for (int r = 0; r < 4; ++r)
          P_lds[(w * 32 + mi * 16 + quad * 4 + r) * 64 + ni * 16 + l15] =
              __float2bfloat16(s_acc[mi][ni][r]);
    for (int mi = 0; mi < 2; ++mi)
      for (int di = 0; di < 4; ++di)
        for (int r = 0; r < 4; ++r) o_acc[mi][di][r] *= alpha[mi][r];
    __syncthreads();  // P visible

    // O += P @ V  (A = P rows, B = V^T rows; both k-contiguous)
    for (int kk = 0; kk < 2; ++kk) {
      bf16x8 a[2], bb[4];
      for (int mi = 0; mi < 2; ++mi)
        a[mi] = *(const bf16x8*)(P_lds + (w * 32 + mi * 16 + l15) * 64 + kk * 32 + quad * 8);
      for (int di = 0; di < 4; ++di)
        bb[di] = *(const bf16x8*)(V_lds + (di * 16 + l15) * 64 + kk * 32 + quad * 8);
      for (int mi = 0; mi < 2; ++mi)
        for (int di = 0; di < 4; ++di)
          o_acc[mi][di] = mfma16(a[mi], bb[di], o_acc[mi][di]);
    }
    __syncthreads();  // PV reads done before next restage / P rewrite
  }

  // normalize + write ctx (B,S,D) bf16 with col = h*64+d
  for (int mi = 0; mi < 2; ++mi)
    for (int r = 0; r < 4; ++r) {
      const float inv = 1.f / l_run[mi][r];
      const int row = q0 + w * 32 + mi * 16 + quad * 4 + r;
      for (int di = 0; di < 4; ++di) {
        const int col = h * DK + di * 16 + l15;
        ctx[(size_t)(b * SEQ + row) * DIM + col] =
            __float2bfloat16(o_acc[mi][di][r] * inv);
      }
    }
}

// ---------------------------------------------------------------------------
// Output projection: out = ctx @ wo^T + bo. ctx bf16, wo fp32, out fp32.
// grid = (8, 32).
// ---------------------------------------------------------------------------
__global__ __launch_bounds__(256) void out_proj_kernel(
    const __hip_bfloat16* __restrict__ ctx, const float* __restrict__ wo,
    const float* __restrict__ bo, float* __restrict__ out) {
  __shared__ __align__(16) __hip_bfloat16 A_lds[128 * 64];
  __shared__ __align__(16) __hip_bfloat16 B_lds[128 * 64];

  const int m0 = blockIdx.y * 128, n0 = blockIdx.x * 128;
  f32x4 acc[4][4];
  gemm_mainloop<false, true>(ctx, wo, A_lds, B_lds, m0, n0, acc);

  const int tid = threadIdx.x, lane = tid & 63, w = tid >> 6;
  const int quad = lane >> 4, l15 = lane & 15;
  const int wm = (w >> 1) * 64, wn = (w & 1) * 64;

  for (int mi = 0; mi < 4; ++mi)
    for (int ni = 0; ni < 4; ++ni) {
      const int n = n0 + wn + ni * 16 + l15;
      const float bv_ = bo[n];
      for (int r = 0; r < 4; ++r) {
        const int m = m0 + wm + mi * 16 + quad * 4 + r;
        out[(size_t)m * DIM + n] = acc[mi][ni][r] + bv_;
      }
    }
}

extern "C" void kernel_launch(void* const* d_in, const int* in_sizes, int n_in,
                              void* d_out, int out_size, void* d_ws, size_t ws_size,
                              hipStream_t stream) {
  const float* query = (const float*)d_in[0];
  const float* key   = (const float*)d_in[1];
  const float* value = (const float*)d_in[2];
  const int*   mask  = (const int*)d_in[3];
  const float* wq = (const float*)d_in[4];
  const float* bq = (const float*)d_in[5];
  const float* wk = (const float*)d_in[6];
  const float* bk = (const float*)d_in[7];
  const float* wv = (const float*)d_in[8];
  const float* bv = (const float*)d_in[9];
  const float* wo = (const float*)d_in[10];
  const float* bo = (const float*)d_in[11];
  float* out = (float*)d_out;

  char* ws = (char*)d_ws;
  const size_t TEN = (size_t)2 * NH * SEQ * DK * sizeof(__hip_bfloat16);  // 8 MiB
  __hip_bfloat16* q_ws   = (__hip_bfloat16*)(ws);
  __hip_bfloat16* k_ws   = (__hip_bfloat16*)(ws + TEN);
  __hip_bfloat16* vt_ws  = (__hip_bfloat16*)(ws + 2 * TEN);
  __hip_bfloat16* ctx_ws = (__hip_bfloat16*)(ws + 3 * TEN);

  dim3 blk(256);
  qkv_proj_kernel<<<dim3(8, 32, 3), blk, 0, stream>>>(
      query, key, value, wq, wk, wv, bq, bk, bv, q_ws, k_ws, vt_ws);
  attn_kernel<<<dim3(16, 32), blk, 0, stream>>>(q_ws, k_ws, vt_ws, mask, ctx_ws);
  out_proj_kernel<<<dim3(8, 32), blk, 0, stream>>>(ctx_ws, wo, bo, out);
}

// Round 4
// 281.557 us; speedup vs baseline: 1.3662x; 1.3662x over previous
//
#include <hip/hip_runtime.h>
#include <hip/hip_bf16.h>

// B=2, S=2048, D=1024, H=16, dk=64. fp32 in/out; bf16 MFMA compute.
// ws (58.7 MB): xq@0 (later ctx), xk, xv, wqb..wob, q, k, vt.
#define SEQ 2048
#define DIM 1024
#define NH  16
#define DK  64
#define NA  (2 * SEQ * DIM)   // activation elems
#define NW  (DIM * DIM)       // weight elems
#define PSTR 72               // padded P row stride (bf16): conflict-free b64/b128
#define QSCALE 0.18033688011112042f  // 0.125 * log2(e): exp2 domain

typedef __attribute__((ext_vector_type(4))) float f32x4;
typedef __attribute__((ext_vector_type(8))) __bf16 bf16x8;
typedef __attribute__((ext_vector_type(4))) __bf16 bf16x4;

__device__ __forceinline__ f32x4 mfma16(bf16x8 a, bf16x8 b, f32x4 c) {
  return __builtin_amdgcn_mfma_f32_16x16x32_bf16(a, b, c, 0, 0, 0);
}
__device__ __forceinline__ void async_load16(const void* g, void* l) {
  __builtin_amdgcn_global_load_lds(
      (const __attribute__((address_space(1))) void*)g,
      (__attribute__((address_space(3))) void*)l, 16, 0, 0);
}

// ---------------------------------------------------------------------------
// fp32 -> bf16 conversion for all operands. grid (2048, 7); 8 elems/thread.
// ---------------------------------------------------------------------------
__global__ __launch_bounds__(256) void cvt_kernel(
    const float* __restrict__ s0, const float* __restrict__ s1,
    const float* __restrict__ s2, const float* __restrict__ s3,
    const float* __restrict__ s4, const float* __restrict__ s5,
    const float* __restrict__ s6,
    __hip_bfloat16* __restrict__ d0, __hip_bfloat16* __restrict__ d1,
    __hip_bfloat16* __restrict__ d2, __hip_bfloat16* __restrict__ d3,
    __hip_bfloat16* __restrict__ d4, __hip_bfloat16* __restrict__ d5,
    __hip_bfloat16* __restrict__ d6) {
  const int t = blockIdx.y;
  const float* s;
  __hip_bfloat16* d;
  int n;
  switch (t) {
    case 0: s = s0; d = d0; n = NA; break;
    case 1: s = s1; d = d1; n = NA; break;
    case 2: s = s2; d = d2; n = NA; break;
    case 3: s = s3; d = d3; n = NW; break;
    case 4: s = s4; d = d4; n = NW; break;
    case 5: s = s5; d = d5; n = NW; break;
    default: s = s6; d = d6; n = NW; break;
  }
  size_t i = ((size_t)blockIdx.x * 256 + threadIdx.x) * 8;
  if (i >= (size_t)n) return;
  float4 a = *(const float4*)(s + i);
  float4 b = *(const float4*)(s + i + 4);
  bf16x8 v = {(__bf16)a.x, (__bf16)a.y, (__bf16)a.z, (__bf16)a.w,
              (__bf16)b.x, (__bf16)b.y, (__bf16)b.z, (__bf16)b.w};
  *(bf16x8*)(d + i) = v;
}

// ---------------------------------------------------------------------------
// m97-style async NT-GEMM mainloop, pure bf16: C = X @ W^T, 128x128 tile.
// ---------------------------------------------------------------------------
__device__ __forceinline__ void gemm_mainloop(
    const __hip_bfloat16* __restrict__ X, const __hip_bfloat16* __restrict__ W,
    __hip_bfloat16* A_lds, __hip_bfloat16* B_lds, int m0, int n0,
    f32x4 acc[4][4]) {
  const int K = DIM;
  const int tid = threadIdx.x, lane = tid & 63, w = tid >> 6;
  const int quad = lane >> 4, l15 = lane & 15;
  const int wm = (w >> 1) * 64, wn = (w & 1) * 64;

  f32x4 z = {0.f, 0.f, 0.f, 0.f};
  for (int mi = 0; mi < 4; ++mi)
    for (int ni = 0; ni < 4; ++ni) acc[mi][ni] = z;

  for (int k0 = 0; k0 < K; k0 += 64) {
    for (int r = 0; r < 4; ++r) {
      int cbase = r * 256 + w * 64;
      int c = cbase + lane, row = c >> 3, off = c & 7;
      async_load16((const char*)(X + (size_t)(m0 + row) * K + k0) + off * 16,
                   (char*)A_lds + cbase * 16);
      async_load16((const char*)(W + (size_t)(n0 + row) * K + k0) + off * 16,
                   (char*)B_lds + cbase * 16);
    }
    __syncthreads();
    for (int kk = 0; kk < 2; ++kk) {
      bf16x8 a[4], b[4];
      for (int mi = 0; mi < 4; ++mi)
        a[mi] = *(const bf16x8*)(A_lds + (wm + mi * 16 + l15) * 64 + kk * 32 + quad * 8);
      for (int ni = 0; ni < 4; ++ni)
        b[ni] = *(const bf16x8*)(B_lds + (wn + ni * 16 + l15) * 64 + kk * 32 + quad * 8);
      for (int mi = 0; mi < 4; ++mi)
        for (int ni = 0; ni < 4; ++ni)
          acc[mi][ni] = mfma16(a[mi], b[ni], acc[mi][ni]);
    }
    __syncthreads();
  }
}

// ---------------------------------------------------------------------------
// QKV projection, all-bf16. grid (8, 32, 3). q pre-scaled by QSCALE (exp2
// softmax domain); k as-is; v transposed (B,H,dk,S).
// ---------------------------------------------------------------------------
__global__ __launch_bounds__(256) void qkv_proj_kernel(
    const __hip_bfloat16* __restrict__ xq, const __hip_bfloat16* __restrict__ xk,
    const __hip_bfloat16* __restrict__ xv,
    const __hip_bfloat16* __restrict__ wq, const __hip_bfloat16* __restrict__ wk,
    const __hip_bfloat16* __restrict__ wv,
    const float* __restrict__ bq, const float* __restrict__ bk,
    const float* __restrict__ bv,
    __hip_bfloat16* __restrict__ q_ws, __hip_bfloat16* __restrict__ k_ws,
    __hip_bfloat16* __restrict__ vt_ws) {
  __shared__ __align__(16) __hip_bfloat16 A_lds[128 * 64];
  __shared__ __align__(16) __hip_bfloat16 B_lds[128 * 64];

  const int z = blockIdx.z;
  const __hip_bfloat16* X = (z == 0) ? xq : ((z == 1) ? xk : xv);
  const __hip_bfloat16* W = (z == 0) ? wq : ((z == 1) ? wk : wv);
  const float* bias = (z == 0) ? bq : ((z == 1) ? bk : bv);
  __hip_bfloat16* out = (z == 0) ? q_ws : ((z == 1) ? k_ws : vt_ws);
  const float f = (z == 0) ? QSCALE : 1.0f;

  const int m0 = blockIdx.y * 128, n0 = blockIdx.x * 128;
  f32x4 acc[4][4];
  gemm_mainloop(X, W, A_lds, B_lds, m0, n0, acc);

  const int tid = threadIdx.x, lane = tid & 63, w = tid >> 6;
  const int quad = lane >> 4, l15 = lane & 15;
  const int wm = (w >> 1) * 64, wn = (w & 1) * 64;

  for (int mi = 0; mi < 4; ++mi)
    for (int ni = 0; ni < 4; ++ni) {
      const int n = n0 + wn + ni * 16 + l15;
      const float bv_ = bias[n];
      const int h = n >> 6, d = n & 63;
      for (int r = 0; r < 4; ++r) {
        const int m = m0 + wm + mi * 16 + quad * 4 + r;
        const int b = m >> 11, s = m & 2047;
        const float v = (acc[mi][ni][r] + bv_) * f;
        size_t addr;
        if (z == 2)
          addr = ((size_t)(b * NH + h) * DK + d) * SEQ + s;   // v transposed
        else
          addr = ((size_t)(b * NH + h) * SEQ + s) * DK + d;   // q,k
        out[addr] = __float2bfloat16(v);
      }
    }
}

// ---------------------------------------------------------------------------
// Flash attention, S^T formulation. grid (16, 32), 4 waves, wave w owns
// q-rows [w*32, w*32+32). St = K·Q^T (C-layout: col=qrow, rows=4 consec keys
// per reg quad) -> P stored [qrow][key] with b64 packs, stride 72 (bank-clean).
// No-running-max softmax in exp2 domain (scale folded into q). O^T = V^T·P^T.
// ---------------------------------------------------------------------------
__global__ __launch_bounds__(256) void attn_kernel(
    const __hip_bfloat16* __restrict__ qg, const __hip_bfloat16* __restrict__ kg,
    const __hip_bfloat16* __restrict__ vtg, const int* __restrict__ mask,
    __hip_bfloat16* __restrict__ ctx) {
  __shared__ __align__(16) __hip_bfloat16 Q_lds[128 * 64];
  __shared__ __align__(16) __hip_bfloat16 K_lds[64 * 64];
  __shared__ __align__(16) __hip_bfloat16 V_lds[64 * 64];   // V^T tile [d][key]
  __shared__ __align__(16) __hip_bfloat16 P_lds[128 * PSTR];
  __shared__ float bias_lds[SEQ];                            // key mask bias

  const int tid = threadIdx.x, lane = tid & 63, w = tid >> 6;
  const int quad = lane >> 4, l15 = lane & 15;
  const int bh = blockIdx.y, b = bh >> 4, h = bh & 15;
  const int q0 = blockIdx.x * 128;
  const size_t head = (size_t)bh * SEQ * DK;

  for (int i = tid; i < SEQ; i += 256)
    bias_lds[i] = mask[b * SEQ + i] ? 0.f : -1e9f;

  // stage Q tile (128x64) async
  for (int r = 0; r < 4; ++r) {
    int cbase = r * 256 + w * 64;
    int c = cbase + lane, row = c >> 3, off = c & 7;
    async_load16((const char*)(qg + head + (size_t)(q0 + row) * DK) + off * 16,
                 (char*)Q_lds + cbase * 16);
  }
  __syncthreads();

  int qmv[2];
  for (int ni = 0; ni < 2; ++ni)
    qmv[ni] = mask[b * SEQ + q0 + w * 32 + ni * 16 + l15];

  f32x4 z = {0.f, 0.f, 0.f, 0.f};
  f32x4 o_acc[2][4];  // [ni(qrow grp)][di(d grp)], O^T C-layout
  for (int ni = 0; ni < 2; ++ni)
    for (int di = 0; di < 4; ++di) o_acc[ni][di] = z;
  float lsum[2] = {0.f, 0.f};

  for (int t = 0; t < 32; ++t) {
    const int k0 = t * 64;
    for (int r = 0; r < 2; ++r) {
      int cbase = r * 256 + w * 64;
      int c = cbase + lane, row = c >> 3, off = c & 7;
      async_load16((const char*)(kg + head + (size_t)(k0 + row) * DK) + off * 16,
                   (char*)K_lds + cbase * 16);
      async_load16(
          (const char*)(vtg + (size_t)bh * DK * SEQ + (size_t)row * SEQ + k0) + off * 16,
          (char*)V_lds + cbase * 16);
    }
    __syncthreads();  // staging visible

    // St = K Q^T : D[key][qrow]; wave tile 64 keys x 32 qrows
    f32x4 s_acc[4][2];
    for (int mi = 0; mi < 4; ++mi)
      for (int ni = 0; ni < 2; ++ni) s_acc[mi][ni] = z;
    for (int kk = 0; kk < 2; ++kk) {
      bf16x8 ak[4], bq[2];
      for (int mi = 0; mi < 4; ++mi)
        ak[mi] = *(const bf16x8*)(K_lds + (mi * 16 + l15) * 64 + kk * 32 + quad * 8);
      for (int ni = 0; ni < 2; ++ni)
        bq[ni] = *(const bf16x8*)(Q_lds + (w * 32 + ni * 16 + l15) * 64 + kk * 32 + quad * 8);
      for (int mi = 0; mi < 4; ++mi)
        for (int ni = 0; ni < 2; ++ni)
          s_acc[mi][ni] = mfma16(ak[mi], bq[ni], s_acc[mi][ni]);
    }

    // key bias + qrow select + exp2 + lsum + P[qrow][key] b64 store
    for (int mi = 0; mi < 4; ++mi) {
      f32x4 kb = *(const f32x4*)(bias_lds + k0 + mi * 16 + quad * 4);
      for (int ni = 0; ni < 2; ++ni) {
        bf16x4 pk;
        for (int r = 0; r < 4; ++r) {
          float s2 = s_acc[mi][ni][r] + kb[r];
          s2 = qmv[ni] ? s2 : 0.f;   // masked q-row -> uniform softmax
          float p = __builtin_amdgcn_exp2f(s2);
          lsum[ni] += p;
          pk[r] = (__bf16)p;
        }
        *(bf16x4*)(P_lds + (w * 32 + ni * 16 + l15) * PSTR + mi * 16 + quad * 4) = pk;
      }
    }
    // (no barrier: P rows are wave-local; compiler orders ds_write->ds_read)

    // O^T += V^T P^T : D[d][qrow]
    for (int kk = 0; kk < 2; ++kk) {
      bf16x8 av[4], bp[2];
      for (int di = 0; di < 4; ++di)
        av[di] = *(const bf16x8*)(V_lds + (di * 16 + l15) * 64 + kk * 32 + quad * 8);
      for (int ni = 0; ni < 2; ++ni)
        bp[ni] = *(const bf16x8*)(P_lds + (w * 32 + ni * 16 + l15) * PSTR + kk * 32 + quad * 8);
      for (int ni = 0; ni < 2; ++ni)
        for (int di = 0; di < 4; ++di)
          o_acc[ni][di] = mfma16(av[di], bp[ni], o_acc[ni][di]);
    }
    __syncthreads();  // K/V reads done before restage
  }

  // final l reduction across quads (rows live in l15; quads hold key-partials)
  for (int ni = 0; ni < 2; ++ni) {
    lsum[ni] += __shfl_xor(lsum[ni], 16);
    lsum[ni] += __shfl_xor(lsum[ni], 32);
  }
  const float inv[2] = {1.f / lsum[0], 1.f / lsum[1]};

  // O^T -> LDS [qrow][d] (b64 packs, wave-local rows), then coalesced ctx store
  for (int ni = 0; ni < 2; ++ni)
    for (int di = 0; di < 4; ++di) {
      bf16x4 ov;
      for (int r = 0; r < 4; ++r) ov[r] = (__bf16)(o_acc[ni][di][r] * inv[ni]);
      *(bf16x4*)(P_lds + (w * 32 + ni * 16 + l15) * PSTR + di * 16 + quad * 4) = ov;
    }
  __syncthreads();
  for (int r = 0; r < 4; ++r) {
    int c = r * 256 + tid, row = c >> 3, off = c & 7;
    *(uint4*)(ctx + (size_t)(b * SEQ + q0 + row) * DIM + h * DK + off * 8) =
        *(const uint4*)(P_lds + row * PSTR + off * 8);
  }
}

// ---------------------------------------------------------------------------
// Output projection: out = ctx @ wo^T + bo (ctx/wo bf16, out fp32). grid (8,32).
// ---------------------------------------------------------------------------
__global__ __launch_bounds__(256) void out_proj_kernel(
    const __hip_bfloat16* __restrict__ ctx, const __hip_bfloat16* __restrict__ wo,
    const float* __restrict__ bo, float* __restrict__ out) {
  __shared__ __align__(16) __hip_bfloat16 A_lds[128 * 64];
  __shared__ __align__(16) __hip_bfloat16 B_lds[128 * 64];

  const int m0 = blockIdx.y * 128, n0 = blockIdx.x * 128;
  f32x4 acc[4][4];
  gemm_mainloop(ctx, wo, A_lds, B_lds, m0, n0, acc);

  const int tid = threadIdx.x, lane = tid & 63, w = tid >> 6;
  const int quad = lane >> 4, l15 = lane & 15;
  const int wm = (w >> 1) * 64, wn = (w & 1) * 64;

  for (int mi = 0; mi < 4; ++mi)
    for (int ni = 0; ni < 4; ++ni) {
      const int n = n0 + wn + ni * 16 + l15;
      const float bv_ = bo[n];
      for (int r = 0; r < 4; ++r) {
        const int m = m0 + wm + mi * 16 + quad * 4 + r;
        out[(size_t)m * DIM + n] = acc[mi][ni][r] + bv_;
      }
    }
}

extern "C" void kernel_launch(void* const* d_in, const int* in_sizes, int n_in,
                              void* d_out, int out_size, void* d_ws, size_t ws_size,
                              hipStream_t stream) {
  const float* query = (const float*)d_in[0];
  const float* key   = (const float*)d_in[1];
  const float* value = (const float*)d_in[2];
  const int*   mask  = (const int*)d_in[3];
  const float* wq = (const float*)d_in[4];
  const float* bq = (const float*)d_in[5];
  const float* wk = (const float*)d_in[6];
  const float* bk = (const float*)d_in[7];
  const float* wv = (const float*)d_in[8];
  const float* bv = (const float*)d_in[9];
  const float* wo = (const float*)d_in[10];
  const float* bo = (const float*)d_in[11];
  float* out = (float*)d_out;

  char* ws = (char*)d_ws;
  const size_t SZA = (size_t)NA * 2;  // 8 MiB bf16 activation
  const size_t SZW = (size_t)NW * 2;  // 2 MiB bf16 weight
  __hip_bfloat16* xq  = (__hip_bfloat16*)(ws);
  __hip_bfloat16* xk  = (__hip_bfloat16*)(ws + SZA);
  __hip_bfloat16* xv  = (__hip_bfloat16*)(ws + 2 * SZA);
  __hip_bfloat16* wqb = (__hip_bfloat16*)(ws + 3 * SZA);
  __hip_bfloat16* wkb = (__hip_bfloat16*)(ws + 3 * SZA + SZW);
  __hip_bfloat16* wvb = (__hip_bfloat16*)(ws + 3 * SZA + 2 * SZW);
  __hip_bfloat16* wob = (__hip_bfloat16*)(ws + 3 * SZA + 3 * SZW);
  __hip_bfloat16* q_ws  = (__hip_bfloat16*)(ws + 3 * SZA + 4 * SZW);
  __hip_bfloat16* k_ws  = (__hip_bfloat16*)(ws + 4 * SZA + 4 * SZW);
  __hip_bfloat16* vt_ws = (__hip_bfloat16*)(ws + 5 * SZA + 4 * SZW);
  __hip_bfloat16* ctx_ws = xq;  // xq dead after qkv_proj

  dim3 blk(256);
  cvt_kernel<<<dim3(2048, 7), blk, 0, stream>>>(
      query, key, value, wq, wk, wv, wo, xq, xk, xv, wqb, wkb, wvb, wob);
  qkv_proj_kernel<<<dim3(8, 32, 3), blk, 0, stream>>>(
      xq, xk, xv, wqb, wkb, wvb, bq, bk, bv, q_ws, k_ws, vt_ws);
  attn_kernel<<<dim3(16, 32), blk, 0, stream>>>(q_ws, k_ws, vt_ws, mask, ctx_ws);
  out_proj_kernel<<<dim3(8, 32), blk, 0, stream>>>(ctx_ws, wob, bo, out);
}

// Round 5
// 263.290 us; speedup vs baseline: 1.4610x; 1.0694x over previous
//
#include <hip/hip_runtime.h>
#include <hip/hip_bf16.h>

// B=2, S=2048, D=1024, H=16, dk=64. fp32 in/out; bf16 MFMA compute.
// ws (58.7 MB): xq@0 (later ctx), xk, xv, wqb..wob, q, k, vt.
#define SEQ 2048
#define DIM 1024
#define NH  16
#define DK  64
#define NA  (2 * SEQ * DIM)   // activation elems
#define NW  (DIM * DIM)       // weight elems
#define PSTR 72               // padded P row stride (bf16): conflict-free b64/b128
#define QSCALE 0.18033688011112042f  // 0.125 * log2(e): exp2 domain

typedef __attribute__((ext_vector_type(4))) float f32x4;
typedef __attribute__((ext_vector_type(8))) __bf16 bf16x8;
typedef __attribute__((ext_vector_type(4))) __bf16 bf16x4;

__device__ __forceinline__ f32x4 mfma16(bf16x8 a, bf16x8 b, f32x4 c) {
  return __builtin_amdgcn_mfma_f32_16x16x32_bf16(a, b, c, 0, 0, 0);
}
__device__ __forceinline__ void async_load16(const void* g, void* l) {
  __builtin_amdgcn_global_load_lds(
      (const __attribute__((address_space(1))) void*)g,
      (__attribute__((address_space(3))) void*)l, 16, 0, 0);
}
// XOR-swizzled 16B-chunk slot for a [rows x 64bf16] tile: kills the
// stride-128B bank collision on column-fragment reads (2-way max = free).
__device__ __forceinline__ int swz(int row, int chunk) {
  return row * 8 + (chunk ^ (row & 7));
}

// ---------------------------------------------------------------------------
// fp32 -> bf16 conversion for all operands. grid (2048, 7); 8 elems/thread.
// ---------------------------------------------------------------------------
__global__ __launch_bounds__(256) void cvt_kernel(
    const float* __restrict__ s0, const float* __restrict__ s1,
    const float* __restrict__ s2, const float* __restrict__ s3,
    const float* __restrict__ s4, const float* __restrict__ s5,
    const float* __restrict__ s6,
    __hip_bfloat16* __restrict__ d0, __hip_bfloat16* __restrict__ d1,
    __hip_bfloat16* __restrict__ d2, __hip_bfloat16* __restrict__ d3,
    __hip_bfloat16* __restrict__ d4, __hip_bfloat16* __restrict__ d5,
    __hip_bfloat16* __restrict__ d6) {
  const int t = blockIdx.y;
  const float* s;
  __hip_bfloat16* d;
  int n;
  switch (t) {
    case 0: s = s0; d = d0; n = NA; break;
    case 1: s = s1; d = d1; n = NA; break;
    case 2: s = s2; d = d2; n = NA; break;
    case 3: s = s3; d = d3; n = NW; break;
    case 4: s = s4; d = d4; n = NW; break;
    case 5: s = s5; d = d5; n = NW; break;
    default: s = s6; d = d6; n = NW; break;
  }
  size_t i = ((size_t)blockIdx.x * 256 + threadIdx.x) * 8;
  if (i >= (size_t)n) return;
  float4 a = *(const float4*)(s + i);
  float4 b = *(const float4*)(s + i + 4);
  bf16x8 v = {(__bf16)a.x, (__bf16)a.y, (__bf16)a.z, (__bf16)a.w,
              (__bf16)b.x, (__bf16)b.y, (__bf16)b.z, (__bf16)b.w};
  *(bf16x8*)(d + i) = v;
}

// ---------------------------------------------------------------------------
// m97-style async NT-GEMM mainloop, bf16, XOR-swizzled LDS tiles.
// C = X @ W^T, 128x128 tile, 4 waves x (64x64).
// ---------------------------------------------------------------------------
__device__ __forceinline__ void gemm_mainloop(
    const __hip_bfloat16* __restrict__ X, const __hip_bfloat16* __restrict__ W,
    __hip_bfloat16* A_lds, __hip_bfloat16* B_lds, int m0, int n0,
    f32x4 acc[4][4]) {
  const int K = DIM;
  const int tid = threadIdx.x, lane = tid & 63, w = tid >> 6;
  const int quad = lane >> 4, l15 = lane & 15;
  const int wm = (w >> 1) * 64, wn = (w & 1) * 64;

  f32x4 z = {0.f, 0.f, 0.f, 0.f};
  for (int mi = 0; mi < 4; ++mi)
    for (int ni = 0; ni < 4; ++ni) acc[mi][ni] = z;

  for (int k0 = 0; k0 < K; k0 += 64) {
    for (int r = 0; r < 4; ++r) {
      int cbase = r * 256 + w * 64;
      int c = cbase + lane, row = c >> 3, cs = c & 7;
      int off = cs ^ (row & 7);  // swizzled source chunk
      async_load16((const char*)(X + (size_t)(m0 + row) * K + k0) + off * 16,
                   (char*)A_lds + cbase * 16);
      async_load16((const char*)(W + (size_t)(n0 + row) * K + k0) + off * 16,
                   (char*)B_lds + cbase * 16);
    }
    __syncthreads();
    for (int kk = 0; kk < 2; ++kk) {
      bf16x8 a[4], b[4];
      for (int mi = 0; mi < 4; ++mi)
        a[mi] = *(const bf16x8*)(A_lds + swz(wm + mi * 16 + l15, kk * 4 + quad) * 8);
      for (int ni = 0; ni < 4; ++ni)
        b[ni] = *(const bf16x8*)(B_lds + swz(wn + ni * 16 + l15, kk * 4 + quad) * 8);
      for (int mi = 0; mi < 4; ++mi)
        for (int ni = 0; ni < 4; ++ni)
          acc[mi][ni] = mfma16(a[mi], b[ni], acc[mi][ni]);
    }
    __syncthreads();
  }
}

// ---------------------------------------------------------------------------
// QKV projection, all-bf16. grid (8, 32, 3). q pre-scaled by QSCALE (exp2
// softmax domain); k as-is; v transposed (B,H,dk,S).
// ---------------------------------------------------------------------------
__global__ __launch_bounds__(256) void qkv_proj_kernel(
    const __hip_bfloat16* __restrict__ xq, const __hip_bfloat16* __restrict__ xk,
    const __hip_bfloat16* __restrict__ xv,
    const __hip_bfloat16* __restrict__ wq, const __hip_bfloat16* __restrict__ wk,
    const __hip_bfloat16* __restrict__ wv,
    const float* __restrict__ bq, const float* __restrict__ bk,
    const float* __restrict__ bv,
    __hip_bfloat16* __restrict__ q_ws, __hip_bfloat16* __restrict__ k_ws,
    __hip_bfloat16* __restrict__ vt_ws) {
  __shared__ __align__(16) __hip_bfloat16 A_lds[128 * 64];
  __shared__ __align__(16) __hip_bfloat16 B_lds[128 * 64];

  const int z = blockIdx.z;
  const __hip_bfloat16* X = (z == 0) ? xq : ((z == 1) ? xk : xv);
  const __hip_bfloat16* W = (z == 0) ? wq : ((z == 1) ? wk : wv);
  const float* bias = (z == 0) ? bq : ((z == 1) ? bk : bv);
  __hip_bfloat16* out = (z == 0) ? q_ws : ((z == 1) ? k_ws : vt_ws);
  const float f = (z == 0) ? QSCALE : 1.0f;

  const int m0 = blockIdx.y * 128, n0 = blockIdx.x * 128;
  f32x4 acc[4][4];
  gemm_mainloop(X, W, A_lds, B_lds, m0, n0, acc);

  const int tid = threadIdx.x, lane = tid & 63, w = tid >> 6;
  const int quad = lane >> 4, l15 = lane & 15;
  const int wm = (w >> 1) * 64, wn = (w & 1) * 64;

  for (int mi = 0; mi < 4; ++mi)
    for (int ni = 0; ni < 4; ++ni) {
      const int n = n0 + wn + ni * 16 + l15;
      const float bv_ = bias[n];
      const int h = n >> 6, d = n & 63;
      for (int r = 0; r < 4; ++r) {
        const int m = m0 + wm + mi * 16 + quad * 4 + r;
        const int b = m >> 11, s = m & 2047;
        const float v = (acc[mi][ni][r] + bv_) * f;
        size_t addr;
        if (z == 2)
          addr = ((size_t)(b * NH + h) * DK + d) * SEQ + s;   // v transposed
        else
          addr = ((size_t)(b * NH + h) * SEQ + s) * DK + d;   // q,k
        out[addr] = __float2bfloat16(v);
      }
    }
}

// ---------------------------------------------------------------------------
// Flash attention, S^T formulation. grid (16, 32), 4 waves, wave w owns
// q-rows [w*32, w*32+32). Q fragments hoisted to registers; Q LDS unioned
// with P (43 KB total -> 3 blocks/CU). St = K·Q^T, exp2 softmax (no running
// max; scale folded into q), P[qrow][key] stride-72 (bank-clean), O^T = V^T·P^T.
// ---------------------------------------------------------------------------
__global__ __launch_bounds__(256) void attn_kernel(
    const __hip_bfloat16* __restrict__ qg, const __hip_bfloat16* __restrict__ kg,
    const __hip_bfloat16* __restrict__ vtg, const int* __restrict__ mask,
    __hip_bfloat16* __restrict__ ctx) {
  __shared__ __align__(16) __hip_bfloat16 QP_lds[128 * PSTR];  // Q tile, then P
  __shared__ __align__(16) __hip_bfloat16 K_lds[64 * 64];
  __shared__ __align__(16) __hip_bfloat16 V_lds[64 * 64];      // V^T tile [d][key]
  __shared__ float bias_lds[SEQ];                              // key mask bias

  const int tid = threadIdx.x, lane = tid & 63, w = tid >> 6;
  const int quad = lane >> 4, l15 = lane & 15;
  const int bh = blockIdx.y, b = bh >> 4, h = bh & 15;
  const int q0 = blockIdx.x * 128;
  const size_t head = (size_t)bh * SEQ * DK;

  for (int i = tid; i < SEQ; i += 256)
    bias_lds[i] = mask[b * SEQ + i] ? 0.f : -1e9f;

  // stage Q tile (128x64) async, swizzled
  for (int r = 0; r < 4; ++r) {
    int cbase = r * 256 + w * 64;
    int c = cbase + lane, row = c >> 3, cs = c & 7;
    int off = cs ^ (row & 7);
    async_load16((const char*)(qg + head + (size_t)(q0 + row) * DK) + off * 16,
                 (char*)QP_lds + cbase * 16);
  }
  __syncthreads();

  // hoist Q fragments (loop-invariant) -> QP_lds becomes P storage after
  // the iter-0 post-staging barrier (all waves read before any P write).
  bf16x8 qf[2][2];  // [kk][ni]
  for (int kk = 0; kk < 2; ++kk)
    for (int ni = 0; ni < 2; ++ni)
      qf[kk][ni] = *(const bf16x8*)(QP_lds + swz(w * 32 + ni * 16 + l15, kk * 4 + quad) * 8);

  int qmv[2];
  for (int ni = 0; ni < 2; ++ni)
    qmv[ni] = mask[b * SEQ + q0 + w * 32 + ni * 16 + l15];

  __hip_bfloat16* P_lds = QP_lds;

  f32x4 z = {0.f, 0.f, 0.f, 0.f};
  f32x4 o_acc[2][4];  // [ni(qrow grp)][di(d grp)], O^T C-layout
  for (int ni = 0; ni < 2; ++ni)
    for (int di = 0; di < 4; ++di) o_acc[ni][di] = z;
  float lsum[2] = {0.f, 0.f};

  for (int t = 0; t < 32; ++t) {
    const int k0 = t * 64;
    for (int r = 0; r < 2; ++r) {
      int cbase = r * 256 + w * 64;
      int c = cbase + lane, row = c >> 3, cs = c & 7;
      int off = cs ^ (row & 7);
      async_load16((const char*)(kg + head + (size_t)(k0 + row) * DK) + off * 16,
                   (char*)K_lds + cbase * 16);
      async_load16(
          (const char*)(vtg + (size_t)bh * DK * SEQ + (size_t)row * SEQ + k0) + off * 16,
          (char*)V_lds + cbase * 16);
    }
    __syncthreads();  // staging visible

    // St = K Q^T : D[key][qrow]; wave tile 64 keys x 32 qrows
    f32x4 s_acc[4][2];
    for (int mi = 0; mi < 4; ++mi)
      for (int ni = 0; ni < 2; ++ni) s_acc[mi][ni] = z;
    for (int kk = 0; kk < 2; ++kk) {
      bf16x8 ak[4];
      for (int mi = 0; mi < 4; ++mi)
        ak[mi] = *(const bf16x8*)(K_lds + swz(mi * 16 + l15, kk * 4 + quad) * 8);
      for (int mi = 0; mi < 4; ++mi)
        for (int ni = 0; ni < 2; ++ni)
          s_acc[mi][ni] = mfma16(ak[mi], qf[kk][ni], s_acc[mi][ni]);
    }

    // key bias + qrow select + exp2 + lsum + P[qrow][key] b64 store
    for (int mi = 0; mi < 4; ++mi) {
      f32x4 kb = *(const f32x4*)(bias_lds + k0 + mi * 16 + quad * 4);
      for (int ni = 0; ni < 2; ++ni) {
        bf16x4 pk;
        for (int r = 0; r < 4; ++r) {
          float s2 = s_acc[mi][ni][r] + kb[r];
          s2 = qmv[ni] ? s2 : 0.f;   // masked q-row -> uniform softmax
          float p = __builtin_amdgcn_exp2f(s2);
          lsum[ni] += p;
          pk[r] = (__bf16)p;
        }
        *(bf16x4*)(P_lds + (w * 32 + ni * 16 + l15) * PSTR + mi * 16 + quad * 4) = pk;
      }
    }
    // (no barrier: P rows are wave-local; lgkmcnt orders ds_write->ds_read)

    // O^T += V^T P^T : D[d][qrow]
    for (int kk = 0; kk < 2; ++kk) {
      bf16x8 av[4], bp[2];
      for (int di = 0; di < 4; ++di)
        av[di] = *(const bf16x8*)(V_lds + swz(di * 16 + l15, kk * 4 + quad) * 8);
      for (int ni = 0; ni < 2; ++ni)
        bp[ni] = *(const bf16x8*)(P_lds + (w * 32 + ni * 16 + l15) * PSTR + kk * 32 + quad * 8);
      for (int ni = 0; ni < 2; ++ni)
        for (int di = 0; di < 4; ++di)
          o_acc[ni][di] = mfma16(av[di], bp[ni], o_acc[ni][di]);
    }
    __syncthreads();  // K/V reads done before restage
  }

  // final l reduction across quads (rows live in l15; quads hold key-partials)
  for (int ni = 0; ni < 2; ++ni) {
    lsum[ni] += __shfl_xor(lsum[ni], 16);
    lsum[ni] += __shfl_xor(lsum[ni], 32);
  }
  const float inv[2] = {1.f / lsum[0], 1.f / lsum[1]};

  // O^T -> LDS [qrow][d] (b64 packs, wave-local rows), then coalesced ctx store
  for (int ni = 0; ni < 2; ++ni)
    for (int di = 0; di < 4; ++di) {
      bf16x4 ov;
      for (int r = 0; r < 4; ++r) ov[r] = (__bf16)(o_acc[ni][di][r] * inv[ni]);
      *(bf16x4*)(P_lds + (w * 32 + ni * 16 + l15) * PSTR + di * 16 + quad * 4) = ov;
    }
  __syncthreads();
  for (int r = 0; r < 4; ++r) {
    int c = r * 256 + tid, row = c >> 3, off = c & 7;
    *(uint4*)(ctx + (size_t)(b * SEQ + q0 + row) * DIM + h * DK + off * 8) =
        *(const uint4*)(P_lds + row * PSTR + off * 8);
  }
}

// ---------------------------------------------------------------------------
// Output projection: out = ctx @ wo^T + bo (ctx/wo bf16, out fp32). grid (8,32).
// ---------------------------------------------------------------------------
__global__ __launch_bounds__(256) void out_proj_kernel(
    const __hip_bfloat16* __restrict__ ctx, const __hip_bfloat16* __restrict__ wo,
    const float* __restrict__ bo, float* __restrict__ out) {
  __shared__ __align__(16) __hip_bfloat16 A_lds[128 * 64];
  __shared__ __align__(16) __hip_bfloat16 B_lds[128 * 64];

  const int m0 = blockIdx.y * 128, n0 = blockIdx.x * 128;
  f32x4 acc[4][4];
  gemm_mainloop(ctx, wo, A_lds, B_lds, m0, n0, acc);

  const int tid = threadIdx.x, lane = tid & 63, w = tid >> 6;
  const int quad = lane >> 4, l15 = lane & 15;
  const int wm = (w >> 1) * 64, wn = (w & 1) * 64;

  for (int mi = 0; mi < 4; ++mi)
    for (int ni = 0; ni < 4; ++ni) {
      const int n = n0 + wn + ni * 16 + l15;
      const float bv_ = bo[n];
      for (int r = 0; r < 4; ++r) {
        const int m = m0 + wm + mi * 16 + quad * 4 + r;
        out[(size_t)m * DIM + n] = acc[mi][ni][r] + bv_;
      }
    }
}

extern "C" void kernel_launch(void* const* d_in, const int* in_sizes, int n_in,
                              void* d_out, int out_size, void* d_ws, size_t ws_size,
                              hipStream_t stream) {
  const float* query = (const float*)d_in[0];
  const float* key   = (const float*)d_in[1];
  const float* value = (const float*)d_in[2];
  const int*   mask  = (const int*)d_in[3];
  const float* wq = (const float*)d_in[4];
  const float* bq = (const float*)d_in[5];
  const float* wk = (const float*)d_in[6];
  const float* bk = (const float*)d_in[7];
  const float* wv = (const float*)d_in[8];
  const float* bv = (const float*)d_in[9];
  const float* wo = (const float*)d_in[10];
  const float* bo = (const float*)d_in[11];
  float* out = (float*)d_out;

  char* ws = (char*)d_ws;
  const size_t SZA = (size_t)NA * 2;  // 8 MiB bf16 activation
  const size_t SZW = (size_t)NW * 2;  // 2 MiB bf16 weight
  __hip_bfloat16* xq  = (__hip_bfloat16*)(ws);
  __hip_bfloat16* xk  = (__hip_bfloat16*)(ws + SZA);
  __hip_bfloat16* xv  = (__hip_bfloat16*)(ws + 2 * SZA);
  __hip_bfloat16* wqb = (__hip_bfloat16*)(ws + 3 * SZA);
  __hip_bfloat16* wkb = (__hip_bfloat16*)(ws + 3 * SZA + SZW);
  __hip_bfloat16* wvb = (__hip_bfloat16*)(ws + 3 * SZA + 2 * SZW);
  __hip_bfloat16* wob = (__hip_bfloat16*)(ws + 3 * SZA + 3 * SZW);
  __hip_bfloat16* q_ws  = (__hip_bfloat16*)(ws + 3 * SZA + 4 * SZW);
  __hip_bfloat16* k_ws  = (__hip_bfloat16*)(ws + 4 * SZA + 4 * SZW);
  __hip_bfloat16* vt_ws = (__hip_bfloat16*)(ws + 5 * SZA + 4 * SZW);
  __hip_bfloat16* ctx_ws = xq;  // xq dead after qkv_proj

  dim3 blk(256);
  cvt_kernel<<<dim3(2048, 7), blk, 0, stream>>>(
      query, key, value, wq, wk, wv, wo, xq, xk, xv, wqb, wkb, wvb, wob);
  qkv_proj_kernel<<<dim3(8, 32, 3), blk, 0, stream>>>(
      xq, xk, xv, wqb, wkb, wvb, bq, bk, bv, q_ws, k_ws, vt_ws);
  attn_kernel<<<dim3(16, 32), blk, 0, stream>>>(q_ws, k_ws, vt_ws, mask, ctx_ws);
  out_proj_kernel<<<dim3(8, 32), blk, 0, stream>>>(ctx_ws, wob, bo, out);
}

// Round 6
// 239.569 us; speedup vs baseline: 1.6056x; 1.0990x over previous
//
#include <hip/hip_runtime.h>
#include <hip/hip_bf16.h>

// B=2, S=2048, D=1024, H=16, dk=64. fp32 in/out; bf16 MFMA compute.
#define SEQ 2048
#define DIM 1024
#define NH  16
#define DK  64
#define NA  (2 * SEQ * DIM)   // activation elems
#define NW  (DIM * DIM)       // weight elems
#define PSTR 72               // padded P row stride (bf16)
#define TSTR 132              // padded transpose-tile stride (bf16)
#define QSCALE 0.18033688011112042f  // 0.125 * log2(e)

typedef __attribute__((ext_vector_type(4))) float f32x4;
typedef __attribute__((ext_vector_type(8))) __bf16 bf16x8;
typedef __attribute__((ext_vector_type(4))) __bf16 bf16x4;

__device__ __forceinline__ f32x4 mfma16(bf16x8 a, bf16x8 b, f32x4 c) {
  return __builtin_amdgcn_mfma_f32_16x16x32_bf16(a, b, c, 0, 0, 0);
}
__device__ __forceinline__ void async_load16(const void* g, void* l) {
  __builtin_amdgcn_global_load_lds(
      (const __attribute__((address_space(1))) void*)g,
      (__attribute__((address_space(3))) void*)l, 16, 0, 0);
}
// XOR-swizzled 16B-chunk slot for a [rows x 64bf16] tile.
__device__ __forceinline__ int swz(int row, int chunk) {
  return row * 8 + (chunk ^ (row & 7));
}

// ---------------------------------------------------------------------------
// fp32 -> bf16 conversion for all operands. grid (2048, 7); 8 elems/thread.
// ---------------------------------------------------------------------------
__global__ __launch_bounds__(256) void cvt_kernel(
    const float* __restrict__ s0, const float* __restrict__ s1,
    const float* __restrict__ s2, const float* __restrict__ s3,
    const float* __restrict__ s4, const float* __restrict__ s5,
    const float* __restrict__ s6,
    __hip_bfloat16* __restrict__ d0, __hip_bfloat16* __restrict__ d1,
    __hip_bfloat16* __restrict__ d2, __hip_bfloat16* __restrict__ d3,
    __hip_bfloat16* __restrict__ d4, __hip_bfloat16* __restrict__ d5,
    __hip_bfloat16* __restrict__ d6) {
  const int t = blockIdx.y;
  const float* s;
  __hip_bfloat16* d;
  int n;
  switch (t) {
    case 0: s = s0; d = d0; n = NA; break;
    case 1: s = s1; d = d1; n = NA; break;
    case 2: s = s2; d = d2; n = NA; break;
    case 3: s = s3; d = d3; n = NW; break;
    case 4: s = s4; d = d4; n = NW; break;
    case 5: s = s5; d = d5; n = NW; break;
    default: s = s6; d = d6; n = NW; break;
  }
  size_t i = ((size_t)blockIdx.x * 256 + threadIdx.x) * 8;
  if (i >= (size_t)n) return;
  float4 a = *(const float4*)(s + i);
  float4 b = *(const float4*)(s + i + 4);
  bf16x8 v = {(__bf16)a.x, (__bf16)a.y, (__bf16)a.z, (__bf16)a.w,
              (__bf16)b.x, (__bf16)b.y, (__bf16)b.z, (__bf16)b.w};
  *(bf16x8*)(d + i) = v;
}

// ---------------------------------------------------------------------------
// m97-style async NT-GEMM mainloop, bf16, XOR-swizzled LDS tiles.
// C = X @ W^T, 128x128 tile, 4 waves x (64x64).
// ---------------------------------------------------------------------------
__device__ __forceinline__ void gemm_mainloop(
    const __hip_bfloat16* __restrict__ X, const __hip_bfloat16* __restrict__ W,
    __hip_bfloat16* A_lds, __hip_bfloat16* B_lds, int m0, int n0,
    f32x4 acc[4][4]) {
  const int K = DIM;
  const int tid = threadIdx.x, lane = tid & 63, w = tid >> 6;
  const int quad = lane >> 4, l15 = lane & 15;
  const int wm = (w >> 1) * 64, wn = (w & 1) * 64;

  f32x4 z = {0.f, 0.f, 0.f, 0.f};
  for (int mi = 0; mi < 4; ++mi)
    for (int ni = 0; ni < 4; ++ni) acc[mi][ni] = z;

  for (int k0 = 0; k0 < K; k0 += 64) {
    for (int r = 0; r < 4; ++r) {
      int cbase = r * 256 + w * 64;
      int c = cbase + lane, row = c >> 3, cs = c & 7;
      int off = cs ^ (row & 7);  // swizzled source chunk
      async_load16((const char*)(X + (size_t)(m0 + row) * K + k0) + off * 16,
                   (char*)A_lds + cbase * 16);
      async_load16((const char*)(W + (size_t)(n0 + row) * K + k0) + off * 16,
                   (char*)B_lds + cbase * 16);
    }
    __syncthreads();
    for (int kk = 0; kk < 2; ++kk) {
      bf16x8 a[4], b[4];
      for (int mi = 0; mi < 4; ++mi)
        a[mi] = *(const bf16x8*)(A_lds + swz(wm + mi * 16 + l15, kk * 4 + quad) * 8);
      for (int ni = 0; ni < 4; ++ni)
        b[ni] = *(const bf16x8*)(B_lds + swz(wn + ni * 16 + l15, kk * 4 + quad) * 8);
      for (int mi = 0; mi < 4; ++mi)
        for (int ni = 0; ni < 4; ++ni)
          acc[mi][ni] = mfma16(a[mi], b[ni], acc[mi][ni]);
    }
    __syncthreads();
  }
}

// ---------------------------------------------------------------------------
// QKV projection. grid (8, 32, 3). q pre-scaled by QSCALE; k direct;
// v written TRANSPOSED (B,H,dk,S) via an LDS transpose (coalesced stores).
// S_lds: A/B staging during mainloop, transpose tile in z==2 epilogue.
// ---------------------------------------------------------------------------
__global__ __launch_bounds__(256) void qkv_proj_kernel(
    const __hip_bfloat16* __restrict__ xq, const __hip_bfloat16* __restrict__ xk,
    const __hip_bfloat16* __restrict__ xv,
    const __hip_bfloat16* __restrict__ wq, const __hip_bfloat16* __restrict__ wk,
    const __hip_bfloat16* __restrict__ wv,
    const float* __restrict__ bq, const float* __restrict__ bk,
    const float* __restrict__ bv,
    __hip_bfloat16* __restrict__ q_ws, __hip_bfloat16* __restrict__ k_ws,
    __hip_bfloat16* __restrict__ vt_ws) {
  __shared__ __align__(16) __hip_bfloat16 S_lds[128 * TSTR];  // >= 2*128*64

  const int z = blockIdx.z;
  const __hip_bfloat16* X = (z == 0) ? xq : ((z == 1) ? xk : xv);
  const __hip_bfloat16* W = (z == 0) ? wq : ((z == 1) ? wk : wv);
  const float* bias = (z == 0) ? bq : ((z == 1) ? bk : bv);
  const float f = (z == 0) ? QSCALE : 1.0f;

  const int m0 = blockIdx.y * 128, n0 = blockIdx.x * 128;
  f32x4 acc[4][4];
  gemm_mainloop(X, W, S_lds, S_lds + 128 * 64, m0, n0, acc);

  const int tid = threadIdx.x, lane = tid & 63, w = tid >> 6;
  const int quad = lane >> 4, l15 = lane & 15;
  const int wm = (w >> 1) * 64, wn = (w & 1) * 64;

  if (z != 2) {
    __hip_bfloat16* out = (z == 0) ? q_ws : k_ws;
    for (int mi = 0; mi < 4; ++mi)
      for (int ni = 0; ni < 4; ++ni) {
        const int n = n0 + wn + ni * 16 + l15;
        const float bv_ = bias[n];
        const int h = n >> 6, d = n & 63;
        for (int r = 0; r < 4; ++r) {
          const int m = m0 + wm + mi * 16 + quad * 4 + r;
          const int b = m >> 11, s = m & 2047;
          out[((size_t)(b * NH + h) * SEQ + s) * DK + d] =
              __float2bfloat16((acc[mi][ni][r] + bv_) * f);
        }
      }
  } else {
    // transpose tile through LDS: T[n_local][m_local], stride TSTR
    for (int mi = 0; mi < 4; ++mi)
      for (int ni = 0; ni < 4; ++ni) {
        const int n_local = wn + ni * 16 + l15;
        const float bv_ = bias[n0 + n_local];
        bf16x4 tv;
        for (int r = 0; r < 4; ++r) tv[r] = (__bf16)(acc[mi][ni][r] + bv_);
        *(bf16x4*)(S_lds + n_local * TSTR + wm + mi * 16 + quad * 4) = tv;
      }
    __syncthreads();
    // coalesced store: vt[(b,h,d)][s]; 128 n-rows x 16 chunks of 8 m
    const int b = m0 >> 11, s_base = m0 & 2047;
    for (int r2 = 0; r2 < 8; ++r2) {
      int c2 = r2 * 256 + tid;
      int nrow = c2 >> 4, moff = (c2 & 15) * 8;
      int n = n0 + nrow, h = n >> 6, d = n & 63;
      *(uint4*)(vt_ws + ((size_t)(b * NH + h) * DK + d) * SEQ + s_base + moff) =
          *(const uint4*)(S_lds + nrow * TSTR + moff);
    }
  }
}

// ---------------------------------------------------------------------------
// Flash attention. grid (16, 32) x 512 threads = 8 waves; wave w owns q-rows
// [w*16, w*16+16). St = K·Q^T with key-mask bias in the accumulator init;
// exp2 softmax (no running max; scale folded into q); lsum via ones-MFMA;
// P[qrow][key] stride-72; O^T = V^T·P^T. Q LDS unioned with P.
// ---------------------------------------------------------------------------
__global__ __launch_bounds__(512) void attn_kernel(
    const __hip_bfloat16* __restrict__ qg, const __hip_bfloat16* __restrict__ kg,
    const __hip_bfloat16* __restrict__ vtg, const int* __restrict__ mask,
    __hip_bfloat16* __restrict__ ctx) {
  __shared__ __align__(16) __hip_bfloat16 QP_lds[128 * PSTR];  // Q tile, then P
  __shared__ __align__(16) __hip_bfloat16 K_lds[64 * 64];
  __shared__ __align__(16) __hip_bfloat16 V_lds[64 * 64];      // V^T tile [d][key]
  __shared__ float bias_lds[SEQ];                              // key mask bias

  const int tid = threadIdx.x, lane = tid & 63, w = tid >> 6;
  const int quad = lane >> 4, l15 = lane & 15;
  const int bh = blockIdx.y, b = bh >> 4, h = bh & 15;
  const int q0 = blockIdx.x * 128;
  const size_t head = (size_t)bh * SEQ * DK;

  for (int i = tid; i < SEQ; i += 512)
    bias_lds[i] = mask[b * SEQ + i] ? 0.f : -1e9f;

  // stage Q tile (128x64) async, swizzled: 1024 chunks, 2 rounds
  for (int r = 0; r < 2; ++r) {
    int cbase = r * 512 + w * 64;
    int c = cbase + lane, row = c >> 3, cs = c & 7;
    int off = cs ^ (row & 7);
    async_load16((const char*)(qg + head + (size_t)(q0 + row) * DK) + off * 16,
                 (char*)QP_lds + cbase * 16);
  }
  __syncthreads();

  // hoist Q fragments; QP_lds becomes P after the iter-0 staging barrier
  bf16x8 qf[2];
  for (int kk = 0; kk < 2; ++kk)
    qf[kk] = *(const bf16x8*)(QP_lds + swz(w * 16 + l15, kk * 4 + quad) * 8);
  const int qmv = mask[b * SEQ + q0 + w * 16 + l15];

  __hip_bfloat16* P_lds = QP_lds;
  const bf16x8 ones = {(__bf16)1.f, (__bf16)1.f, (__bf16)1.f, (__bf16)1.f,
                       (__bf16)1.f, (__bf16)1.f, (__bf16)1.f, (__bf16)1.f};

  f32x4 z = {0.f, 0.f, 0.f, 0.f};
  f32x4 o_acc[4];  // [di], O^T C-layout (col = qrow)
  for (int di = 0; di < 4; ++di) o_acc[di] = z;
  f32x4 o_sum = z;  // row-sums of P via ones-MFMA

  for (int t = 0; t < 32; ++t) {
    const int k0 = t * 64;
    {  // stage K (64x64) + V^T (64x64): 512 chunks each, 1 per thread
      int c = tid, row = c >> 3, cs = c & 7;
      int off = cs ^ (row & 7);
      async_load16((const char*)(kg + head + (size_t)(k0 + row) * DK) + off * 16,
                   (char*)K_lds + c * 16);
      async_load16(
          (const char*)(vtg + (size_t)bh * DK * SEQ + (size_t)row * SEQ + k0) + off * 16,
          (char*)V_lds + c * 16);
    }
    __syncthreads();  // staging visible

    // St = K Q^T, bias pre-loaded into accumulator
    f32x4 s_acc[4];
    for (int mi = 0; mi < 4; ++mi)
      s_acc[mi] = *(const f32x4*)(bias_lds + k0 + mi * 16 + quad * 4);
    for (int kk = 0; kk < 2; ++kk) {
      bf16x8 ak[4];
      for (int mi = 0; mi < 4; ++mi)
        ak[mi] = *(const bf16x8*)(K_lds + swz(mi * 16 + l15, kk * 4 + quad) * 8);
      for (int mi = 0; mi < 4; ++mi)
        s_acc[mi] = mfma16(ak[mi], qf[kk], s_acc[mi]);
    }

    // qrow select + exp2 + P[qrow][key] b64 store
    for (int mi = 0; mi < 4; ++mi) {
      bf16x4 pk;
      for (int r = 0; r < 4; ++r) {
        float s2 = qmv ? s_acc[mi][r] : 0.f;  // masked q-row -> uniform
        pk[r] = (__bf16)__builtin_amdgcn_exp2f(s2);
      }
      *(bf16x4*)(P_lds + (w * 16 + l15) * PSTR + mi * 16 + quad * 4) = pk;
    }
    // (no barrier: P rows are wave-local)

    // O^T += V^T P^T ; row-sum via ones-MFMA on the same P fragment
    for (int kk = 0; kk < 2; ++kk) {
      bf16x8 bp = *(const bf16x8*)(P_lds + (w * 16 + l15) * PSTR + kk * 32 + quad * 8);
      bf16x8 av[4];
      for (int di = 0; di < 4; ++di)
        av[di] = *(const bf16x8*)(V_lds + swz(di * 16 + l15, kk * 4 + quad) * 8);
      for (int di = 0; di < 4; ++di)
        o_acc[di] = mfma16(av[di], bp, o_acc[di]);
      o_sum = mfma16(ones, bp, o_sum);
    }
    __syncthreads();  // K/V reads done before restage
  }

  // normalization factor: o_sum col j=l15 holds this lane's qrow sum
  const float inv = 1.f / o_sum[0];

  // O^T -> LDS [qrow][d], then coalesced ctx store
  for (int di = 0; di < 4; ++di) {
    bf16x4 ov;
    for (int r = 0; r < 4; ++r) ov[r] = (__bf16)(o_acc[di][r] * inv);
    *(bf16x4*)(P_lds + (w * 16 + l15) * PSTR + di * 16 + quad * 4) = ov;
  }
  __syncthreads();
  for (int r = 0; r < 2; ++r) {
    int c = r * 512 + tid, row = c >> 3, off = c & 7;
    *(uint4*)(ctx + (size_t)(b * SEQ + q0 + row) * DIM + h * DK + off * 8) =
        *(const uint4*)(P_lds + row * PSTR + off * 8);
  }
}

// ---------------------------------------------------------------------------
// Output projection: out = ctx @ wo^T + bo (ctx/wo bf16, out fp32). grid (8,32).
// ---------------------------------------------------------------------------
__global__ __launch_bounds__(256) void out_proj_kernel(
    const __hip_bfloat16* __restrict__ ctx, const __hip_bfloat16* __restrict__ wo,
    const float* __restrict__ bo, float* __restrict__ out) {
  __shared__ __align__(16) __hip_bfloat16 A_lds[128 * 64];
  __shared__ __align__(16) __hip_bfloat16 B_lds[128 * 64];

  const int m0 = blockIdx.y * 128, n0 = blockIdx.x * 128;
  f32x4 acc[4][4];
  gemm_mainloop(ctx, wo, A_lds, B_lds, m0, n0, acc);

  const int tid = threadIdx.x, lane = tid & 63, w = tid >> 6;
  const int quad = lane >> 4, l15 = lane & 15;
  const int wm = (w >> 1) * 64, wn = (w & 1) * 64;

  for (int mi = 0; mi < 4; ++mi)
    for (int ni = 0; ni < 4; ++ni) {
      const int n = n0 + wn + ni * 16 + l15;
      const float bv_ = bo[n];
      for (int r = 0; r < 4; ++r) {
        const int m = m0 + wm + mi * 16 + quad * 4 + r;
        out[(size_t)m * DIM + n] = acc[mi][ni][r] + bv_;
      }
    }
}

extern "C" void kernel_launch(void* const* d_in, const int* in_sizes, int n_in,
                              void* d_out, int out_size, void* d_ws, size_t ws_size,
                              hipStream_t stream) {
  const float* query = (const float*)d_in[0];
  const float* key   = (const float*)d_in[1];
  const float* value = (const float*)d_in[2];
  const int*   mask  = (const int*)d_in[3];
  const float* wq = (const float*)d_in[4];
  const float* bq = (const float*)d_in[5];
  const float* wk = (const float*)d_in[6];
  const float* bk = (const float*)d_in[7];
  const float* wv = (const float*)d_in[8];
  const float* bv = (const float*)d_in[9];
  const float* wo = (const float*)d_in[10];
  const float* bo = (const float*)d_in[11];
  float* out = (float*)d_out;

  char* ws = (char*)d_ws;
  const size_t SZA = (size_t)NA * 2;  // 8 MiB bf16 activation
  const size_t SZW = (size_t)NW * 2;  // 2 MiB bf16 weight
  __hip_bfloat16* xq  = (__hip_bfloat16*)(ws);
  __hip_bfloat16* xk  = (__hip_bfloat16*)(ws + SZA);
  __hip_bfloat16* xv  = (__hip_bfloat16*)(ws + 2 * SZA);
  __hip_bfloat16* wqb = (__hip_bfloat16*)(ws + 3 * SZA);
  __hip_bfloat16* wkb = (__hip_bfloat16*)(ws + 3 * SZA + SZW);
  __hip_bfloat16* wvb = (__hip_bfloat16*)(ws + 3 * SZA + 2 * SZW);
  __hip_bfloat16* wob = (__hip_bfloat16*)(ws + 3 * SZA + 3 * SZW);
  __hip_bfloat16* q_ws  = (__hip_bfloat16*)(ws + 3 * SZA + 4 * SZW);
  __hip_bfloat16* k_ws  = (__hip_bfloat16*)(ws + 4 * SZA + 4 * SZW);
  __hip_bfloat16* vt_ws = (__hip_bfloat16*)(ws + 5 * SZA + 4 * SZW);
  __hip_bfloat16* ctx_ws = xq;  // xq dead after qkv_proj

  cvt_kernel<<<dim3(2048, 7), dim3(256), 0, stream>>>(
      query, key, value, wq, wk, wv, wo, xq, xk, xv, wqb, wkb, wvb, wob);
  qkv_proj_kernel<<<dim3(8, 32, 3), dim3(256), 0, stream>>>(
      xq, xk, xv, wqb, wkb, wvb, bq, bk, bv, q_ws, k_ws, vt_ws);
  attn_kernel<<<dim3(16, 32), dim3(512), 0, stream>>>(q_ws, k_ws, vt_ws, mask, ctx_ws);
  out_proj_kernel<<<dim3(8, 32), dim3(256), 0, stream>>>(ctx_ws, wob, bo, out);
}

// Round 7
// 238.531 us; speedup vs baseline: 1.6126x; 1.0044x over previous
//
#include <hip/hip_runtime.h>
#include <hip/hip_bf16.h>

// B=2, S=2048, D=1024, H=16, dk=64. fp32 in/out; bf16 MFMA compute.
#define SEQ 2048
#define DIM 1024
#define NH  16
#define DK  64
#define NA  (2 * SEQ * DIM)   // activation elems
#define NW  (DIM * DIM)       // weight elems
#define PSTR 72               // padded P row stride (bf16)
#define ESTR 136              // epilogue bf16 tile stride (16B-aligned rows)
#define FSTR 132              // epilogue fp32 tile stride (16B-aligned rows)
#define QSCALE 0.18033688011112042f  // 0.125 * log2(e)

typedef __attribute__((ext_vector_type(4))) float f32x4;
typedef __attribute__((ext_vector_type(8))) __bf16 bf16x8;
typedef __attribute__((ext_vector_type(4))) __bf16 bf16x4;

__device__ __forceinline__ f32x4 mfma16(bf16x8 a, bf16x8 b, f32x4 c) {
  return __builtin_amdgcn_mfma_f32_16x16x32_bf16(a, b, c, 0, 0, 0);
}
__device__ __forceinline__ void async_load16(const void* g, void* l) {
  __builtin_amdgcn_global_load_lds(
      (const __attribute__((address_space(1))) void*)g,
      (__attribute__((address_space(3))) void*)l, 16, 0, 0);
}
// XOR-swizzled 16B-chunk slot for a [rows x 64bf16] tile.
__device__ __forceinline__ int swz(int row, int chunk) {
  return row * 8 + (chunk ^ (row & 7));
}

// ---------------------------------------------------------------------------
// fp32 -> bf16 conversion, exact 1D grid: 3 act tensors (2048 blocks each) +
// 4 weight tensors (512 blocks each) = 8192 blocks; 8 elems/thread.
// ---------------------------------------------------------------------------
__global__ __launch_bounds__(256) void cvt_kernel(
    const float* __restrict__ s0, const float* __restrict__ s1,
    const float* __restrict__ s2, const float* __restrict__ s3,
    const float* __restrict__ s4, const float* __restrict__ s5,
    const float* __restrict__ s6,
    __hip_bfloat16* __restrict__ d0, __hip_bfloat16* __restrict__ d1,
    __hip_bfloat16* __restrict__ d2, __hip_bfloat16* __restrict__ d3,
    __hip_bfloat16* __restrict__ d4, __hip_bfloat16* __restrict__ d5,
    __hip_bfloat16* __restrict__ d6) {
  const int id = blockIdx.x;
  const float* s;
  __hip_bfloat16* d;
  int bid;
  if (id < 6144) {
    int t = id >> 11;
    bid = id & 2047;
    s = (t == 0) ? s0 : ((t == 1) ? s1 : s2);
    d = (t == 0) ? d0 : ((t == 1) ? d1 : d2);
  } else {
    int t = (id - 6144) >> 9;
    bid = (id - 6144) & 511;
    s = (t == 0) ? s3 : ((t == 1) ? s4 : ((t == 2) ? s5 : s6));
    d = (t == 0) ? d3 : ((t == 1) ? d4 : ((t == 2) ? d5 : d6));
  }
  size_t i = ((size_t)bid * 256 + threadIdx.x) * 8;
  float4 a = *(const float4*)(s + i);
  float4 b = *(const float4*)(s + i + 4);
  bf16x8 v = {(__bf16)a.x, (__bf16)a.y, (__bf16)a.z, (__bf16)a.w,
              (__bf16)b.x, (__bf16)b.y, (__bf16)b.z, (__bf16)b.w};
  *(bf16x8*)(d + i) = v;
}

// ---------------------------------------------------------------------------
// m97-style async NT-GEMM mainloop, bf16, XOR-swizzled LDS tiles.
// C = X @ W^T, 128x128 tile, 4 waves x (64x64).
// ---------------------------------------------------------------------------
__device__ __forceinline__ void gemm_mainloop(
    const __hip_bfloat16* __restrict__ X, const __hip_bfloat16* __restrict__ W,
    __hip_bfloat16* A_lds, __hip_bfloat16* B_lds, int m0, int n0,
    f32x4 acc[4][4]) {
  const int K = DIM;
  const int tid = threadIdx.x, lane = tid & 63, w = tid >> 6;
  const int quad = lane >> 4, l15 = lane & 15;
  const int wm = (w >> 1) * 64, wn = (w & 1) * 64;

  f32x4 z = {0.f, 0.f, 0.f, 0.f};
  for (int mi = 0; mi < 4; ++mi)
    for (int ni = 0; ni < 4; ++ni) acc[mi][ni] = z;

  for (int k0 = 0; k0 < K; k0 += 64) {
    for (int r = 0; r < 4; ++r) {
      int cbase = r * 256 + w * 64;
      int c = cbase + lane, row = c >> 3, cs = c & 7;
      int off = cs ^ (row & 7);  // swizzled source chunk
      async_load16((const char*)(X + (size_t)(m0 + row) * K + k0) + off * 16,
                   (char*)A_lds + cbase * 16);
      async_load16((const char*)(W + (size_t)(n0 + row) * K + k0) + off * 16,
                   (char*)B_lds + cbase * 16);
    }
    __syncthreads();
    for (int kk = 0; kk < 2; ++kk) {
      bf16x8 a[4], b[4];
      for (int mi = 0; mi < 4; ++mi)
        a[mi] = *(const bf16x8*)(A_lds + swz(wm + mi * 16 + l15, kk * 4 + quad) * 8);
      for (int ni = 0; ni < 4; ++ni)
        b[ni] = *(const bf16x8*)(B_lds + swz(wn + ni * 16 + l15, kk * 4 + quad) * 8);
      for (int mi = 0; mi < 4; ++mi)
        for (int ni = 0; ni < 4; ++ni)
          acc[mi][ni] = mfma16(a[mi], b[ni], acc[mi][ni]);
    }
    __syncthreads();
  }
}

// ---------------------------------------------------------------------------
// QKV projection. grid (8, 32, 3). q pre-scaled by QSCALE; k direct; both
// stored (B,H,S,dk) via LDS-coalesced epilogue. v stored transposed
// (B,H,dk,S) via LDS transpose. S_lds: staging in mainloop, tiles after.
// ---------------------------------------------------------------------------
__global__ __launch_bounds__(256) void qkv_proj_kernel(
    const __hip_bfloat16* __restrict__ xq, const __hip_bfloat16* __restrict__ xk,
    const __hip_bfloat16* __restrict__ xv,
    const __hip_bfloat16* __restrict__ wq, const __hip_bfloat16* __restrict__ wk,
    const __hip_bfloat16* __restrict__ wv,
    const float* __restrict__ bq, const float* __restrict__ bk,
    const float* __restrict__ bv,
    __hip_bfloat16* __restrict__ q_ws, __hip_bfloat16* __restrict__ k_ws,
    __hip_bfloat16* __restrict__ vt_ws) {
  __shared__ __align__(16) __hip_bfloat16 S_lds[128 * ESTR];  // 34816 B

  const int z = blockIdx.z;
  const __hip_bfloat16* X = (z == 0) ? xq : ((z == 1) ? xk : xv);
  const __hip_bfloat16* W = (z == 0) ? wq : ((z == 1) ? wk : wv);
  const float* bias = (z == 0) ? bq : ((z == 1) ? bk : bv);
  const float f = (z == 0) ? QSCALE : 1.0f;

  const int m0 = blockIdx.y * 128, n0 = blockIdx.x * 128;
  f32x4 acc[4][4];
  gemm_mainloop(X, W, S_lds, S_lds + 128 * 64, m0, n0, acc);

  const int tid = threadIdx.x, lane = tid & 63, w = tid >> 6;
  const int quad = lane >> 4, l15 = lane & 15;
  const int wm = (w >> 1) * 64, wn = (w & 1) * 64;

  if (z != 2) {
    __hip_bfloat16* out = (z == 0) ? q_ws : k_ws;
    // two 64-row windows through LDS, coalesced 16B stores
    for (int p = 0; p < 2; ++p) {
      if ((w >> 1) == p) {
        for (int mi = 0; mi < 4; ++mi)
          for (int ni = 0; ni < 4; ++ni) {
            const float bv_ = bias[n0 + wn + ni * 16 + l15];
            for (int r = 0; r < 4; ++r)
              S_lds[(mi * 16 + quad * 4 + r) * ESTR + wn + ni * 16 + l15] =
                  __float2bfloat16((acc[mi][ni][r] + bv_) * f);
          }
      }
      __syncthreads();
      for (int r2 = 0; r2 < 4; ++r2) {
        int c = r2 * 256 + tid;
        int row = c >> 4, j = c & 15;
        int m = m0 + p * 64 + row, b = m >> 11, s = m & 2047;
        int n = n0 + j * 8, h = n >> 6, d = n & 63;
        *(uint4*)(out + ((size_t)(b * NH + h) * SEQ + s) * DK + d) =
            *(const uint4*)(S_lds + row * ESTR + j * 8);
      }
      __syncthreads();
    }
  } else {
    // transpose tile through LDS: T[n_local][m_local]
    for (int mi = 0; mi < 4; ++mi)
      for (int ni = 0; ni < 4; ++ni) {
        const int n_local = wn + ni * 16 + l15;
        const float bv_ = bias[n0 + n_local];
        bf16x4 tv;
        for (int r = 0; r < 4; ++r) tv[r] = (__bf16)(acc[mi][ni][r] + bv_);
        *(bf16x4*)(S_lds + n_local * ESTR + wm + mi * 16 + quad * 4) = tv;
      }
    __syncthreads();
    const int b = m0 >> 11, s_base = m0 & 2047;
    for (int r2 = 0; r2 < 8; ++r2) {
      int c2 = r2 * 256 + tid;
      int nrow = c2 >> 4, moff = (c2 & 15) * 8;
      int n = n0 + nrow, h = n >> 6, d = n & 63;
      *(uint4*)(vt_ws + ((size_t)(b * NH + h) * DK + d) * SEQ + s_base + moff) =
          *(const uint4*)(S_lds + nrow * ESTR + moff);
    }
  }
}

// ---------------------------------------------------------------------------
// Flash attention. grid (16, 32) x 512 threads = 8 waves; wave w owns q-rows
// [w*16, w*16+16). K/V double-buffered -> ONE barrier per iter (staging for
// t+1 issued before compute(t); end-of-iter barrier's vmcnt drain overlaps
// with compute). St = K·Q^T with key-mask bias in accumulator; exp2 softmax
// (scale folded into q); lsum via ones-MFMA; P stride-72; O^T = V^T·P^T.
// ---------------------------------------------------------------------------
__global__ __launch_bounds__(512) void attn_kernel(
    const __hip_bfloat16* __restrict__ qg, const __hip_bfloat16* __restrict__ kg,
    const __hip_bfloat16* __restrict__ vtg, const int* __restrict__ mask,
    __hip_bfloat16* __restrict__ ctx) {
  __shared__ __align__(16) __hip_bfloat16 QP_lds[128 * PSTR];   // Q, then P
  __shared__ __align__(16) __hip_bfloat16 K_lds[2][64 * 64];
  __shared__ __align__(16) __hip_bfloat16 V_lds[2][64 * 64];    // V^T [d][key]
  __shared__ float bias_lds[SEQ];                               // key mask bias

  const int tid = threadIdx.x, lane = tid & 63, w = tid >> 6;
  const int quad = lane >> 4, l15 = lane & 15;
  const int bh = blockIdx.y, b = bh >> 4, h = bh & 15;
  const int q0 = blockIdx.x * 128;
  const size_t head = (size_t)bh * SEQ * DK;
  const size_t vthead = (size_t)bh * DK * SEQ;

  for (int i = tid; i < SEQ; i += 512)
    bias_lds[i] = mask[b * SEQ + i] ? 0.f : -1e9f;

  // stage Q tile (128x64) swizzled: 1024 chunks, 2 rounds
  for (int r = 0; r < 2; ++r) {
    int cbase = r * 512 + w * 64;
    int c = cbase + lane, row = c >> 3, cs = c & 7;
    int off = cs ^ (row & 7);
    async_load16((const char*)(qg + head + (size_t)(q0 + row) * DK) + off * 16,
                 (char*)QP_lds + cbase * 16);
  }
  // stage K/V tile 0 into buffer 0: 512 chunks each, 1/thread
  {
    int row = tid >> 3, cs = tid & 7;
    int off = cs ^ (row & 7);
    async_load16((const char*)(kg + head + (size_t)row * DK) + off * 16,
                 (char*)K_lds[0] + tid * 16);
    async_load16((const char*)(vtg + vthead + (size_t)row * SEQ) + off * 16,
                 (char*)V_lds[0] + tid * 16);
  }
  __syncthreads();

  // hoist Q fragments; QP_lds becomes P (each wave's Q rows == its P rows)
  bf16x8 qf[2];
  for (int kk = 0; kk < 2; ++kk)
    qf[kk] = *(const bf16x8*)(QP_lds + swz(w * 16 + l15, kk * 4 + quad) * 8);
  const int qmv = mask[b * SEQ + q0 + w * 16 + l15];

  __hip_bfloat16* P_lds = QP_lds;
  const bf16x8 ones = {(__bf16)1.f, (__bf16)1.f, (__bf16)1.f, (__bf16)1.f,
                       (__bf16)1.f, (__bf16)1.f, (__bf16)1.f, (__bf16)1.f};

  f32x4 z = {0.f, 0.f, 0.f, 0.f};
  f32x4 o_acc[4];
  for (int di = 0; di < 4; ++di) o_acc[di] = z;
  f32x4 o_sum = z;

  for (int t = 0; t < 32; ++t) {
    const int cur = t & 1;
    if (t < 31) {  // prefetch t+1 into the other buffer (overlaps compute)
      const int k1 = (t + 1) * 64;
      int row = tid >> 3, cs = tid & 7;
      int off = cs ^ (row & 7);
      async_load16((const char*)(kg + head + (size_t)(k1 + row) * DK) + off * 16,
                   (char*)K_lds[1 - cur] + tid * 16);
      async_load16((const char*)(vtg + vthead + (size_t)row * SEQ + k1) + off * 16,
                   (char*)V_lds[1 - cur] + tid * 16);
    }
    const int k0 = t * 64;

    // St = K Q^T, bias pre-loaded into accumulator
    f32x4 s_acc[4];
    for (int mi = 0; mi < 4; ++mi)
      s_acc[mi] = *(const f32x4*)(bias_lds + k0 + mi * 16 + quad * 4);
    for (int kk = 0; kk < 2; ++kk) {
      bf16x8 ak[4];
      for (int mi = 0; mi < 4; ++mi)
        ak[mi] = *(const bf16x8*)(K_lds[cur] + swz(mi * 16 + l15, kk * 4 + quad) * 8);
      for (int mi = 0; mi < 4; ++mi)
        s_acc[mi] = mfma16(ak[mi], qf[kk], s_acc[mi]);
    }

    // qrow select + exp2 + P[qrow][key] b64 store (wave-local)
    for (int mi = 0; mi < 4; ++mi) {
      bf16x4 pk;
      for (int r = 0; r < 4; ++r) {
        float s2 = qmv ? s_acc[mi][r] : 0.f;
        pk[r] = (__bf16)__builtin_amdgcn_exp2f(s2);
      }
      *(bf16x4*)(P_lds + (w * 16 + l15) * PSTR + mi * 16 + quad * 4) = pk;
    }

    // O^T += V^T P^T ; row-sums via ones-MFMA
    for (int kk = 0; kk < 2; ++kk) {
      bf16x8 bp = *(const bf16x8*)(P_lds + (w * 16 + l15) * PSTR + kk * 32 + quad * 8);
      bf16x8 av[4];
      for (int di = 0; di < 4; ++di)
        av[di] = *(const bf16x8*)(V_lds[cur] + swz(di * 16 + l15, kk * 4 + quad) * 8);
      for (int di = 0; di < 4; ++di)
        o_acc[di] = mfma16(av[di], bp, o_acc[di]);
      o_sum = mfma16(ones, bp, o_sum);
    }
    __syncthreads();  // t+1 staging complete; all waves done with P/K/V
  }

  const float inv = 1.f / o_sum[0];

  // O^T -> LDS [qrow][d], then coalesced ctx store
  for (int di = 0; di < 4; ++di) {
    bf16x4 ov;
    for (int r = 0; r < 4; ++r) ov[r] = (__bf16)(o_acc[di][r] * inv);
    *(bf16x4*)(P_lds + (w * 16 + l15) * PSTR + di * 16 + quad * 4) = ov;
  }
  __syncthreads();
  for (int r = 0; r < 2; ++r) {
    int c = r * 512 + tid, row = c >> 3, off = c & 7;
    *(uint4*)(ctx + (size_t)(b * SEQ + q0 + row) * DIM + h * DK + off * 8) =
        *(const uint4*)(P_lds + row * PSTR + off * 8);
  }
}

// ---------------------------------------------------------------------------
// Output projection: out = ctx @ wo^T + bo (bf16 in, fp32 out). grid (8,32).
// LDS-coalesced fp32 epilogue (two 64-row windows).
// ---------------------------------------------------------------------------
__global__ __launch_bounds__(256) void out_proj_kernel(
    const __hip_bfloat16* __restrict__ ctx, const __hip_bfloat16* __restrict__ wo,
    const float* __restrict__ bo, float* __restrict__ out) {
  __shared__ __align__(16) __hip_bfloat16 S_lds[64 * FSTR * 2];  // 33792 B

  const int m0 = blockIdx.y * 128, n0 = blockIdx.x * 128;
  f32x4 acc[4][4];
  gemm_mainloop(ctx, wo, S_lds, S_lds + 128 * 64, m0, n0, acc);

  const int tid = threadIdx.x, lane = tid & 63, w = tid >> 6;
  const int quad = lane >> 4, l15 = lane & 15;
  const int wn = (w & 1) * 64;
  float* epi = (float*)S_lds;

  for (int p = 0; p < 2; ++p) {
    if ((w >> 1) == p) {
      for (int mi = 0; mi < 4; ++mi)
        for (int ni = 0; ni < 4; ++ni) {
          const float bv_ = bo[n0 + wn + ni * 16 + l15];
          for (int r = 0; r < 4; ++r)
            epi[(mi * 16 + quad * 4 + r) * FSTR + wn + ni * 16 + l15] =
                acc[mi][ni][r] + bv_;
        }
    }
    __syncthreads();
    for (int r2 = 0; r2 < 8; ++r2) {
      int c = r2 * 256 + tid;
      int row = c >> 5, j = c & 31;
      *(float4*)(out + (size_t)(m0 + p * 64 + row) * DIM + n0 + j * 4) =
          *(const float4*)(epi + row * FSTR + j * 4);
    }
    __syncthreads();
  }
}

extern "C" void kernel_launch(void* const* d_in, const int* in_sizes, int n_in,
                              void* d_out, int out_size, void* d_ws, size_t ws_size,
                              hipStream_t stream) {
  const float* query = (const float*)d_in[0];
  const float* key   = (const float*)d_in[1];
  const float* value = (const float*)d_in[2];
  const int*   mask  = (const int*)d_in[3];
  const float* wq = (const float*)d_in[4];
  const float* bq = (const float*)d_in[5];
  const float* wk = (const float*)d_in[6];
  const float* bk = (const float*)d_in[7];
  const float* wv = (const float*)d_in[8];
  const float* bv = (const float*)d_in[9];
  const float* wo = (const float*)d_in[10];
  const float* bo = (const float*)d_in[11];
  float* out = (float*)d_out;

  char* ws = (char*)d_ws;
  const size_t SZA = (size_t)NA * 2;  // 8 MiB bf16 activation
  const size_t SZW = (size_t)NW * 2;  // 2 MiB bf16 weight
  __hip_bfloat16* xq  = (__hip_bfloat16*)(ws);
  __hip_bfloat16* xk  = (__hip_bfloat16*)(ws + SZA);
  __hip_bfloat16* xv  = (__hip_bfloat16*)(ws + 2 * SZA);
  __hip_bfloat16* wqb = (__hip_bfloat16*)(ws + 3 * SZA);
  __hip_bfloat16* wkb = (__hip_bfloat16*)(ws + 3 * SZA + SZW);
  __hip_bfloat16* wvb = (__hip_bfloat16*)(ws + 3 * SZA + 2 * SZW);
  __hip_bfloat16* wob = (__hip_bfloat16*)(ws + 3 * SZA + 3 * SZW);
  __hip_bfloat16* q_ws  = (__hip_bfloat16*)(ws + 3 * SZA + 4 * SZW);
  __hip_bfloat16* k_ws  = (__hip_bfloat16*)(ws + 4 * SZA + 4 * SZW);
  __hip_bfloat16* vt_ws = (__hip_bfloat16*)(ws + 5 * SZA + 4 * SZW);
  __hip_bfloat16* ctx_ws = xq;  // xq dead after qkv_proj

  cvt_kernel<<<dim3(8192), dim3(256), 0, stream>>>(
      query, key, value, wq, wk, wv, wo, xq, xk, xv, wqb, wkb, wvb, wob);
  qkv_proj_kernel<<<dim3(8, 32, 3), dim3(256), 0, stream>>>(
      xq, xk, xv, wqb, wkb, wvb, bq, bk, bv, q_ws, k_ws, vt_ws);
  attn_kernel<<<dim3(16, 32), dim3(512), 0, stream>>>(q_ws, k_ws, vt_ws, mask, ctx_ws);
  out_proj_kernel<<<dim3(8, 32), dim3(256), 0, stream>>>(ctx_ws, wob, bo, out);
}